// Round 7
// baseline (150.280 us; speedup 1.0000x reference)
//
#include <hip/hip_runtime.h>

typedef float floatx4 __attribute__((ext_vector_type(4)));
typedef _Float16 half2v __attribute__((ext_vector_type(2)));
typedef _Float16 half8 __attribute__((ext_vector_type(8)));

#define Hh 128
#define Ww 256
#define Cc 64
#define COUT 64
#define Bb 4
#define HW (Hh*Ww)
#define VP 74   // LDS V row stride in shorts: 37 dwords ≡ 5 (mod 32) -> <=2-way (free)

// prep (R6, verified): phase-1 streams 8KB runs; phase-2 NHWC 16B slices;
// same-XCD swizzle so interleaved output slices merge in one L2.
// Blocks >= 512: weight repack -> FRAGMENT-MAJOR [kt][mbh][j][ln][8].
__launch_bounds__(512, 4)
__global__ void prep(const float* __restrict__ x, const float* __restrict__ wsrc,
                     _Float16* __restrict__ xn, unsigned short* __restrict__ wdst) {
    const int bid = blockIdx.x;
    const int tid = threadIdx.x;
    if (bid >= 512) {   // weight repack: 512 blocks x 72 elems
        const int i = (bid - 512) * 72 + tid;
        if (tid < 72) { // i = o*576 + c*9 + kt
            const int kt = i % 9, c = (i / 9) % Cc, o = i / (9 * Cc);
            const int mbh = o >> 5, mi = (o >> 4) & 1, r = o & 15;
            const int g = c >> 5, ks = (c >> 3) & 3, s = c & 7;
            const int ln = ks * 16 + r, j = g * 2 + mi;
            _Float16 hv = (_Float16)wsrc[i];
            wdst[(((kt * 2 + mbh) * 4 + j) * 64 + ln) * 8 + s] = *(unsigned short*)&hv;
        }
        return;
    }
    const int cg = bid >> 6;          // channel group (8 ch)
    const int T  = bid & 63;          // tile
    const int b  = T >> 4;
    const int ht = T & 15;            // 8-row h tile
    __shared__ float Tf[64][260];
    const float* src = x + ((size_t)(b * Cc + cg * 8) * Hh + ht * 8) * Ww;
#pragma unroll
    for (int s = 0; s < 8; ++s) {
        const int u   = s * 512 + tid;      // 16B-unit index in [0,4096)
        const int row = u >> 6;             // c*8 + hh
        const int wq  = u & 63;
        const float4 v = *(const float4*)(src + (size_t)(row >> 3) * HW + (row & 7) * Ww + wq * 4);
        *(float4*)&Tf[row][wq * 4] = v;
    }
    __syncthreads();
#pragma unroll
    for (int j2 = 0; j2 < 4; ++j2) {
        const int idx = j2 * 512 + tid;     // hh*256 + w
        const int hh = idx >> 8, w = idx & 255;
        unsigned o4[4];
#pragma unroll
        for (int cp = 0; cp < 4; ++cp) {
            half2v hv;
            hv.x = (_Float16)Tf[(2 * cp) * 8 + hh][w];
            hv.y = (_Float16)Tf[(2 * cp + 1) * 8 + hh][w];
            o4[cp] = *(unsigned*)&hv;
        }
        uint4 u4; u4.x = o4[0]; u4.y = o4[1]; u4.z = o4[2]; u4.w = o4[3];
        *(uint4*)(xn + ((size_t)(b * Hh + ht * 8 + hh) * Ww + w) * 64 + cg * 8) = u4;
    }
}

// lgkm-only barrier: in-flight VMEM survives.
__device__ __forceinline__ void lds_barrier() {
    asm volatile("s_waitcnt lgkmcnt(0)\n\ts_barrier" ::: "memory");
}
// compile-time scheduling fence: pins VMEM issue order around the stage.
__device__ __forceinline__ void sched_fence() {
    asm volatile("" ::: "memory");
}

struct Tap {
    half2v W00, W01, W10, W11;   // packed (w,w) fp16 corner weights
    int a00, a01, a10, a11;      // corner addresses in uint4 (16B) units
};

__device__ __forceinline__ void tap_setup(int kt, int h, int w, float dy, float dx,
                                          int cg, Tap& t) {
    const int ki = kt / 3, kj = kt % 3;
    const float py = (float)(h - 1 + ki) + dy;
    const float px = (float)(w - 1 + kj) + dx;
    const float y0f = floorf(py), x0f = floorf(px);
    const int y0 = (int)y0f, x0 = (int)x0f;
    const float ly = py - y0f, lx = px - x0f;
    const int y1 = y0 + 1, x1 = x0 + 1;
    const bool vy0 = ((unsigned)y0 < Hh), vy1 = ((unsigned)y1 < Hh);
    const bool vx0 = ((unsigned)x0 < Ww), vx1 = ((unsigned)x1 < Ww);
    const float w00 = (vy0 && vx0) ? (1.f - ly) * (1.f - lx) : 0.f;
    const float w01 = (vy0 && vx1) ? (1.f - ly) * lx : 0.f;
    const float w10 = (vy1 && vx0) ? ly * (1.f - lx) : 0.f;
    const float w11 = (vy1 && vx1) ? ly * lx : 0.f;
    _Float16 h00 = (_Float16)w00, h01 = (_Float16)w01;
    _Float16 h10 = (_Float16)w10, h11 = (_Float16)w11;
    t.W00.x = h00; t.W00.y = h00;  t.W01.x = h01; t.W01.y = h01;
    t.W10.x = h10; t.W10.y = h10;  t.W11.x = h11; t.W11.y = h11;
    const int y0c = min(max(y0, 0), Hh - 1), y1c = min(max(y1, 0), Hh - 1);
    const int x0c = min(max(x0, 0), Ww - 1), x1c = min(max(x1, 0), Ww - 1);
    t.a00 = (y0c * Ww + x0c) * 8 + cg;
    t.a01 = (y0c * Ww + x1c) * 8 + cg;
    t.a10 = (y1c * Ww + x0c) * 8 + cg;
    t.a11 = (y1c * Ww + x1c) * 8 + cg;
}

__device__ __forceinline__ void tap_load(const uint4* __restrict__ xb4, const Tap& t,
                                         unsigned (&pf)[16]) {
    *(uint4*)&pf[0]  = xb4[t.a00];
    *(uint4*)&pf[4]  = xb4[t.a01];
    *(uint4*)&pf[8]  = xb4[t.a10];
    *(uint4*)&pf[12] = xb4[t.a11];
}

// R7: weights staged global->LDS once per block (no per-wave duplicate VMEM).
// 2 x global_load_lds(16B) per wave = 8 instrs/block-tap = 64 line-requests
// (was 128 via duplicate per-wave register loads).
__device__ __forceinline__ void gll16(const unsigned short* g, unsigned short* l) {
    __builtin_amdgcn_global_load_lds(
        (const __attribute__((address_space(1))) unsigned int*)g,
        (__attribute__((address_space(3))) unsigned int*)l, 16, 0, 0);
}
__device__ __forceinline__ void stage_w(const unsigned short* __restrict__ wb, int kt,
                                        unsigned short* ldsbuf, int wv, int ln) {
    sched_fence();
    // lane-linear: wave-uniform LDS base + lane*16B matches gsrc + ln*16B
    gll16(wb + kt * 4096 + wv * 1024 + ln * 8,       ldsbuf + wv * 1024);
    gll16(wb + kt * 4096 + wv * 1024 + 512 + ln * 8, ldsbuf + wv * 1024 + 512);
    sched_fence();
}

// ds_read this wave's 4 weight fragments from staged LDS (conflict-free b128)
__device__ __forceinline__ void wf_read(const unsigned short* __restrict__ wl,
                                        half8 (&WF)[4]) {
    WF[0] = *(const half8*)(wl);
    WF[1] = *(const half8*)(wl + 512);
    WF[2] = *(const half8*)(wl + 1024);
    WF[3] = *(const half8*)(wl + 1536);
}

__device__ __forceinline__ void tap_store(const Tap& t, const unsigned (&pf)[16],
                                          unsigned short* __restrict__ vrow) {
    unsigned o[4];
#pragma unroll
    for (int s = 0; s < 4; ++s) {
        half2v v = (*(const half2v*)&pf[s])      * t.W00
                 + (*(const half2v*)&pf[4 + s])  * t.W01
                 + (*(const half2v*)&pf[8 + s])  * t.W10
                 + (*(const half2v*)&pf[12 + s]) * t.W11;
        o[s] = *(unsigned*)&v;
    }
    uint4 u; u.x = o[0]; u.y = o[1]; u.z = o[2]; u.w = o[3];
    *(uint4*)vrow = u;
}

__device__ __forceinline__ void mfma_tap(const half8 (&WF)[4],
                                         const unsigned short* __restrict__ Vbuf,
                                         int nt, int ln, floatx4 (&acc)[2]) {
#pragma unroll
    for (int g = 0; g < 2; ++g) {
        const int pp = nt * 16 + (ln & 15);
        half8 bfrag = *(const half8*)&Vbuf[pp * VP + g * 32 + (ln >> 4) * 8];
        acc[0] = __builtin_amdgcn_mfma_f32_16x16x32_f16(WF[2 * g],     bfrag, acc[0], 0, 0, 0);
        acc[1] = __builtin_amdgcn_mfma_f32_16x16x32_f16(WF[2 * g + 1], bfrag, acc[1], 0, 0, 0);
    }
}

// R7 iteration J (taps 1..8). Per iter:
//   G(J+1) issue -> off(J+3) -> vmcnt(N) [covers stage(J); gathers are
//   compiler-tracked] -> lgkm barrier [WL[J&1], V[(J-1)&1] visible] ->
//   ds_read WF(J) -> stage(J+1) [post-barrier: cannot race readers of
//   WL[(J+1)&1], whose reads completed before this barrier via lgkmcnt(0)]
//   -> MFMA(J-1) -> pack tap J into V[J&1].
// N = VMEM issued after stage(J) (fence-pinned): 4 if G(J+1), +2 if off.
template<int J>
__device__ __forceinline__ void pipe_iter(
    const uint4* __restrict__ xb4, const float* __restrict__ offb,
    const unsigned short* __restrict__ wb,
    unsigned short (&WL)[2][4096],
    const unsigned short* __restrict__ V0, const unsigned short* __restrict__ V1,
    unsigned short* __restrict__ vrow0, unsigned short* __restrict__ vrow1,
    int h, int w, int cg, int nt, int ln, int wv,
    Tap& tp0, Tap& tp1, unsigned (&pf0)[16], unsigned (&pf1)[16],
    half8 (&WF0)[4], half8 (&WF1)[4],
    float& dy0, float& dx0, float& dy1, float& dx1,
    floatx4 (&acc)[2])
{
    constexpr int S = J & 1, P = 1 - S;
    // 1. gathers for tap J+1 -> slot P
    if constexpr (J + 1 <= 8) {
        tap_setup(J + 1, h, w, P ? dy1 : dy0, P ? dx1 : dx0, cg, P ? tp1 : tp0);
        tap_load(xb4, P ? tp1 : tp0, P ? pf1 : pf0);
    }
    // 2. offset refill for tap J+3 into slot P (parity (J+3)&1 == P)
    if constexpr (J + 3 <= 8) {
        (P ? dy1 : dy0) = offb[(2 * (J + 3)) * HW];
        (P ? dx1 : dx0) = offb[(2 * (J + 3) + 1) * HW];
    }
    // 3. wait for stage(J) to land in WL[S]
    constexpr int NVM = (J + 1 <= 8 ? 4 : 0) + (J + 3 <= 8 ? 2 : 0);
    asm volatile("s_waitcnt vmcnt(%0)" :: "n"(NVM) : "memory");
    // 4. barrier: WL[S] + V[P] visible to all waves
    lds_barrier();
    // 5. read this wave's weight fragments for tap J
    wf_read(&WL[S][(wv >> 1) * 2048 + ln * 8], S ? WF1 : WF0);
    // 6. stage weights for tap J+1 -> WL[P]
    if constexpr (J + 1 <= 8) stage_w(wb, J + 1, WL[P], wv, ln);
    // 7. MFMA tap J-1
    mfma_tap(P ? WF1 : WF0, P ? V1 : V0, nt, ln, acc);
    // 8. combine+pack tap J into V[S]
    tap_store(S ? tp1 : tp0, S ? pf1 : pf0, S ? vrow1 : vrow0);
}

__launch_bounds__(256, 4)
__global__ void dcn_mfma(const _Float16* __restrict__ xn,   // NHWC fp16
                         const float* __restrict__ offset,
                         const unsigned short* __restrict__ wb,
                         const float* __restrict__ bias,
                         float* __restrict__ out) {
    __shared__ unsigned short V[2][32 * VP];   // 2 x 4736 B
    __shared__ unsigned short WL[2][4096];     // 2 x 8 KB staged weights

    const int tid = threadIdx.x;
    const int p   = tid >> 3;
    const int cg  = tid & 7;
    const int wv  = tid >> 6;
    const int ln  = tid & 63;

    const int b  = blockIdx.z;
    const int h  = blockIdx.y;
    const int w0 = blockIdx.x * 32;
    const int w  = w0 + p;

    const uint4* xb4  = (const uint4*)(xn + (size_t)b * HW * 64);
    const float* offb = offset + b * 18 * HW + h * Ww + w;
    unsigned short* vrow0 = &V[0][p * VP + cg * 8];
    unsigned short* vrow1 = &V[1][p * VP + cg * 8];

    const int nt = wv & 1;
    const int mb = (wv >> 1) * 2;

    floatx4 acc[2];
    acc[0] = (floatx4)0.f; acc[1] = (floatx4)0.f;

    unsigned pf0[16], pf1[16];
    half8 WF0[4], WF1[4];
    Tap tp0, tp1;

    // prologue: off(0..3); stage(0); G(0),G(1); then mirror of steady state.
    float dy0 = offb[0],        dx0 = offb[HW];         // tap0 -> slot0
    float dy1 = offb[2 * HW],   dx1 = offb[3 * HW];     // tap1 -> slot1
    stage_w(wb, 0, WL[0], wv, ln);
    tap_setup(0, h, w, dy0, dx0, cg, tp0);
    tap_load(xb4, tp0, pf0);
    dy0 = offb[4 * HW]; dx0 = offb[5 * HW];             // tap2 -> slot0
    tap_setup(1, h, w, dy1, dx1, cg, tp1);
    tap_load(xb4, tp1, pf1);
    dy1 = offb[6 * HW]; dx1 = offb[7 * HW];             // tap3 -> slot1
    // stage(0) landed when <=12 younger VMEM outstanding (G0:4,off:2,G1:4,off:2)
    asm volatile("s_waitcnt vmcnt(12)" ::: "memory");
    lds_barrier();
    wf_read(&WL[0][(wv >> 1) * 2048 + ln * 8], WF0);    // WF(0)
    stage_w(wb, 1, WL[1], wv, ln);                      // stage(1)
    tap_store(tp0, pf0, vrow0);                         // tap0 -> V[0]

#define PI(K) pipe_iter<K>(xb4, offb, wb, WL, V[0], V[1], vrow0, vrow1, h, w, cg, nt, ln, wv, \
                           tp0, tp1, pf0, pf1, WF0, WF1, dy0, dx0, dy1, dx1, acc)
    PI(1); PI(2); PI(3); PI(4); PI(5); PI(6); PI(7); PI(8);
#undef PI

    // epilogue: tap 8 MFMA (WF0 = tap8 read at PI(8); V[0] stored at PI(8))
    lds_barrier();
    mfma_tap(WF0, V[0], nt, ln, acc);

    // epilogue: C/D layout col=lane&15 (pos), row=(lane>>4)*4+reg (o)
    float* outp = out + b * COUT * HW + h * Ww;
    const int col = w0 + nt * 16 + (ln & 15);
#pragma unroll
    for (int mi = 0; mi < 2; ++mi)
#pragma unroll
        for (int r = 0; r < 4; ++r) {
            const int o = (mb + mi) * 16 + (ln >> 4) * 4 + r;
            outp[o * HW + col] = acc[mi][r] + bias[o];
        }
}

extern "C" void kernel_launch(void* const* d_in, const int* in_sizes, int n_in,
                              void* d_out, int out_size, void* d_ws, size_t ws_size,
                              hipStream_t stream) {
    const float* x      = (const float*)d_in[0];
    const float* offset = (const float*)d_in[1];
    const float* weight = (const float*)d_in[2];
    const float* bias   = (const float*)d_in[3];
    float* out = (float*)d_out;

    _Float16* xn = (_Float16*)d_ws;                          // 16.8 MiB NHWC fp16
    unsigned short* wb = (unsigned short*)((char*)d_ws + (size_t)Bb * HW * Cc * 2);

    prep<<<dim3(1024), 512, 0, stream>>>(x, weight, xn, wb);
    dcn_mfma<<<dim3(Ww / 32, Hh, Bb), 256, 0, stream>>>(xn, offset, wb, bias, out);
}